// Round 7
// baseline (583.301 us; speedup 1.0000x reference)
//
#include <hip/hip_runtime.h>
#include <cstdint>
#include <cstddef>

// Problem constants
#define B_  256
#define S_  128
#define D_  1024
#define H_  8
#define DH_ 128
#define M_  (B_ * S_)   // 32768 rows

typedef _Float16 half8 __attribute__((ext_vector_type(8)));
typedef float    f32x4 __attribute__((ext_vector_type(4)));

#define GLOAD_LDS16(gp, lp)                                                    \
    __builtin_amdgcn_global_load_lds(                                          \
        (const __attribute__((address_space(1))) void*)(gp),                   \
        (__attribute__((address_space(3))) void*)(lp), 16, 0, 0)

// ---------------------------------------------------------------------------
// Conversion kernels
// ---------------------------------------------------------------------------
__global__ __launch_bounds__(256)
void cvt_code(const float* __restrict__ src, _Float16* __restrict__ dst, int n8)
{
    int i = blockIdx.x * 256 + threadIdx.x;
    if (i >= n8) return;
    const float4* s = (const float4*)src;
    float4 a = s[2 * i], b = s[2 * i + 1];
    half8 o;
    o[0] = (_Float16)a.x; o[1] = (_Float16)a.y; o[2] = (_Float16)a.z; o[3] = (_Float16)a.w;
    o[4] = (_Float16)b.x; o[5] = (_Float16)b.y; o[6] = (_Float16)b.z; o[7] = (_Float16)b.w;
    *(half8*)(dst + (size_t)i * 8) = o;
}

__global__ __launch_bounds__(256)
void cvt_wqkv(const float* __restrict__ Wq, const float* __restrict__ Wk,
              const float* __restrict__ Wv,
              const float* __restrict__ bq, const float* __restrict__ bk,
              const float* __restrict__ bv,
              _Float16* __restrict__ Wt, float* __restrict__ bias_all)
{
    int idx = blockIdx.x * 256 + threadIdx.x;   // 3072*128
    if (idx >= 3072 * 128) return;
    int n = idx >> 7, kc = idx & 127, k = kc * 8;
    int qkv = n >> 10, hf = n & 1023, h = hf >> 7, f = hf & 127;
    const float* W = (qkv == 0 ? Wq : (qkv == 1 ? Wk : Wv))
                     + (size_t)h * D_ * DH_ + (size_t)k * DH_ + f;
    half8 o;
    #pragma unroll
    for (int j = 0; j < 8; ++j) o[j] = (_Float16)W[(size_t)j * DH_];
    *(half8*)(Wt + (size_t)n * 1024 + k) = o;
    if (kc == 0)
        bias_all[n] = (qkv == 0 ? bq : (qkv == 1 ? bk : bv))[h * DH_ + f];
}

__global__ __launch_bounds__(256)
void cvt_wo(const float* __restrict__ Wo, _Float16* __restrict__ Wot)
{
    int idx = blockIdx.x * 256 + threadIdx.x;   // 1024*256
    if (idx >= 1024 * 256) return;
    int n = idx >> 8, kc = idx & 255, k = kc * 8;
    const float* W = Wo + (size_t)k * 1024 + n;
    half8 o;
    #pragma unroll
    for (int j = 0; j < 8; ++j) o[j] = (_Float16)W[(size_t)j * 1024];
    *(half8*)(Wot + (size_t)n * 2048 + k) = o;
}

// ---------------------------------------------------------------------------
// 256x256 8-phase f16 MFMA GEMM.
// ROUND 7: Round-5 sync skeleton (vmcnt -> barrier -> reads: publication-
// correct) + one-phase read-ahead with COUNTED lgkmcnt so each phase's MFMA
// consumes fragments read in the PREVIOUS phase (LDS latency hidden under
// MFMA + barrier skew). Fragment sets: aqA (qm0), aqB (qm1), b0 (qn0,
// re-read at P2), b1 (qn1). Tail of P3 reads aqA',b0' of tile t+1 from the
// half published by P3's own vmcnt(4)+barrier.
// ---------------------------------------------------------------------------
template <bool OUTF32>
__global__ __launch_bounds__(512, 1)
void gemm_f16_8p(const _Float16* __restrict__ A1p, const _Float16* __restrict__ A2p,
                 int K1, const _Float16* __restrict__ Bt,
                 const float* __restrict__ bias, void* __restrict__ outp,
                 int Ntot, int Ktot, int ntn)
{
    __shared__ __align__(16) char lds[131072];

    const int tid = threadIdx.x;
    const int w = tid >> 6, l = tid & 63;
    const int wm = w >> 2, wn = w & 3;
    const int lr = l & 15, lg = l >> 4;

    // Bijective XCD swizzle (gridDim.x % 8 == 0), n-fastest decode.
    const int cpx = gridDim.x >> 3;
    const int bid = blockIdx.x;
    const int swz = (bid & 7) * cpx + (bid >> 3);
    const int m0 = (swz / ntn) * 256, n0 = (swz % ntn) * 256;

    const int NT = Ktot >> 6;

    // staging lane geometry
    const int srow  = l >> 3;                   // row within 8-row chunk
    const int sgcol = ((l & 7) ^ srow) * 8;     // pre-swizzled source col (f16)

    // half: 0=A0, 1=B0, 2=B1, 3=A1
    auto stageHalf = [&](int bufi, int t, int half) {
        const int k0 = t << 6;
        const bool isA = (half == 0) || (half == 3);
        const int hh = (half >= 2) ? 1 : 0;
        char* dst0 = lds + bufi * 65536 + (isA ? 0 : 32768) + hh * 16384;
        if (isA) {
            const _Float16* Asrc; int kc;
            if (k0 < K1) { Asrc = A1p; kc = k0; } else { Asrc = A2p; kc = k0 - K1; }
            #pragma unroll
            for (int i = 0; i < 2; ++i) {
                const int c = i * 8 + w;
                const int row = hh * 128 + c * 8 + srow;
                const _Float16* g = Asrc + (size_t)(m0 + row) * 1024 + kc + sgcol;
                GLOAD_LDS16(g, dst0 + c * 1024);
            }
        } else {
            #pragma unroll
            for (int i = 0; i < 2; ++i) {
                const int c = i * 8 + w;
                const int row = hh * 128 + c * 8 + srow;
                const _Float16* g = Bt + (size_t)(n0 + row) * Ktot + k0 + sgcol;
                GLOAD_LDS16(g, dst0 + c * 1024);
            }
        }
    };

    auto ldA = [&](int bufi, int fi, int ks) -> half8 {
        const int row = fi * 32 + wm * 16 + lr;
        const int pos = (ks * 4 + lg) ^ (row & 7);
        return *(const half8*)(lds + bufi * 65536 + row * 128 + pos * 16);
    };
    auto ldB = [&](int bufi, int fj, int ks) -> half8 {
        const int row = fj * 64 + wn * 16 + lr;
        const int pos = (ks * 4 + lg) ^ (row & 7);
        return *(const half8*)(lds + bufi * 65536 + 32768 + row * 128 + pos * 16);
    };

    f32x4 acc[8][4] = {};
    half8 aqA[4][2], aqB[4][2], b0[2][2], b1[2][2];

    // Prologue: stage tile 0, publish A0/B0, pre-read P0's fragments.
    stageHalf(0, 0, 0); stageHalf(0, 0, 1); stageHalf(0, 0, 2); stageHalf(0, 0, 3);
    asm volatile("s_waitcnt vmcnt(4)" ::: "memory");
    __builtin_amdgcn_s_barrier();
    #pragma unroll
    for (int fi = 0; fi < 4; ++fi)
        #pragma unroll
        for (int ks = 0; ks < 2; ++ks)
            aqA[fi][ks] = ldA(0, fi, ks);
    #pragma unroll
    for (int fj = 0; fj < 2; ++fj)
        #pragma unroll
        for (int ks = 0; ks < 2; ++ks)
            b0[fj][ks] = ldB(0, fj, ks);

    for (int t = 0; t < NT; ++t) {
        const int buf = t & 1;
        const bool nl = (t + 1 < NT);

        // ---- P0: MFMA (qm0 x qn0) on aqA,b0. Read b1 (needs B1(t) published).
        if (nl) {
            stageHalf(buf ^ 1, t + 1, 0);
            asm volatile("s_waitcnt vmcnt(4)" ::: "memory");
        } else {
            asm volatile("s_waitcnt vmcnt(2)" ::: "memory");
        }
        __builtin_amdgcn_s_barrier();
        #pragma unroll
        for (int fj = 0; fj < 2; ++fj)
            #pragma unroll
            for (int ks = 0; ks < 2; ++ks)
                b1[fj][ks] = ldB(buf, fj + 2, ks);
        asm volatile("s_waitcnt lgkmcnt(4)" ::: "memory");
        __builtin_amdgcn_sched_barrier(0);
        __builtin_amdgcn_s_setprio(1);
        #pragma unroll
        for (int ks = 0; ks < 2; ++ks)
            #pragma unroll
            for (int fi = 0; fi < 4; ++fi)
                #pragma unroll
                for (int fj = 0; fj < 2; ++fj)
                    acc[fi][fj] = __builtin_amdgcn_mfma_f32_16x16x32_f16(
                        aqA[fi][ks], b0[fj][ks], acc[fi][fj], 0, 0, 0);
        __builtin_amdgcn_s_setprio(0);
        __builtin_amdgcn_s_barrier();

        // ---- P1: MFMA (qm0 x qn1) on aqA,b1. Read aqB (needs A1(t) published).
        if (nl) {
            stageHalf(buf ^ 1, t + 1, 1);
            asm volatile("s_waitcnt vmcnt(4)" ::: "memory");
        } else {
            asm volatile("s_waitcnt vmcnt(0)" ::: "memory");
        }
        __builtin_amdgcn_s_barrier();
        #pragma unroll
        for (int fi = 0; fi < 4; ++fi)
            #pragma unroll
            for (int ks = 0; ks < 2; ++ks)
                aqB[fi][ks] = ldA(buf, fi + 4, ks);
        asm volatile("s_waitcnt lgkmcnt(8)" ::: "memory");
        __builtin_amdgcn_sched_barrier(0);
        __builtin_amdgcn_s_setprio(1);
        #pragma unroll
        for (int ks = 0; ks < 2; ++ks)
            #pragma unroll
            for (int fi = 0; fi < 4; ++fi)
                #pragma unroll
                for (int fj = 0; fj < 2; ++fj)
                    acc[fi][fj + 2] = __builtin_amdgcn_mfma_f32_16x16x32_f16(
                        aqA[fi][ks], b1[fj][ks], acc[fi][fj + 2], 0, 0, 0);
        __builtin_amdgcn_s_setprio(0);
        __builtin_amdgcn_s_barrier();

        // ---- P2: MFMA (qm1 x qn1) on aqB,b1. Re-read b0 (published long ago).
        if (nl) stageHalf(buf ^ 1, t + 1, 2);
        __builtin_amdgcn_s_barrier();
        #pragma unroll
        for (int fj = 0; fj < 2; ++fj)
            #pragma unroll
            for (int ks = 0; ks < 2; ++ks)
                b0[fj][ks] = ldB(buf, fj, ks);
        asm volatile("s_waitcnt lgkmcnt(4)" ::: "memory");
        __builtin_amdgcn_sched_barrier(0);
        __builtin_amdgcn_s_setprio(1);
        #pragma unroll
        for (int ks = 0; ks < 2; ++ks)
            #pragma unroll
            for (int fi = 0; fi < 4; ++fi)
                #pragma unroll
                for (int fj = 0; fj < 2; ++fj)
                    acc[fi + 4][fj + 2] = __builtin_amdgcn_mfma_f32_16x16x32_f16(
                        aqB[fi][ks], b1[fj][ks], acc[fi + 4][fj + 2], 0, 0, 0);
        __builtin_amdgcn_s_setprio(0);
        __builtin_amdgcn_s_barrier();

        // ---- P3: MFMA (qm1 x qn0) on aqB,b0. Tail: read aqA',b0' of t+1
        //      (published by THIS phase's vmcnt(4)+barrier).
        if (nl) {
            stageHalf(buf ^ 1, t + 1, 3);
            asm volatile("s_waitcnt vmcnt(4)" ::: "memory");
        }
        __builtin_amdgcn_s_barrier();
        asm volatile("s_waitcnt lgkmcnt(0)" ::: "memory");
        __builtin_amdgcn_sched_barrier(0);
        __builtin_amdgcn_s_setprio(1);
        #pragma unroll
        for (int ks = 0; ks < 2; ++ks)
            #pragma unroll
            for (int fi = 0; fi < 4; ++fi)
                #pragma unroll
                for (int fj = 0; fj < 2; ++fj)
                    acc[fi + 4][fj] = __builtin_amdgcn_mfma_f32_16x16x32_f16(
                        aqB[fi][ks], b0[fj][ks], acc[fi + 4][fj], 0, 0, 0);
        __builtin_amdgcn_s_setprio(0);
        if (nl) {
            #pragma unroll
            for (int fi = 0; fi < 4; ++fi)
                #pragma unroll
                for (int ks = 0; ks < 2; ++ks)
                    aqA[fi][ks] = ldA(buf ^ 1, fi, ks);
            #pragma unroll
            for (int fj = 0; fj < 2; ++fj)
                #pragma unroll
                for (int ks = 0; ks < 2; ++ks)
                    b0[fj][ks] = ldB(buf ^ 1, fj, ks);
        }
        __builtin_amdgcn_s_barrier();
    }

    // Epilogue: bias + relu + store
    #pragma unroll
    for (int fi = 0; fi < 8; ++fi) {
        #pragma unroll
        for (int fj = 0; fj < 4; ++fj) {
            const int n = n0 + fj * 64 + wn * 16 + lr;
            const float bs = bias[n];
            #pragma unroll
            for (int rg = 0; rg < 4; ++rg) {
                const int m = m0 + fi * 32 + wm * 16 + lg * 4 + rg;
                float v = acc[fi][fj][rg] + bs;
                v = v > 0.0f ? v : 0.0f;
                if constexpr (OUTF32)
                    ((float*)outp)[(size_t)m * Ntot + n] = v;
                else
                    ((_Float16*)outp)[(size_t)m * Ntot + n] = (_Float16)v;
            }
        }
    }
}

// ---------------------------------------------------------------------------
// MFMA attention + PDG normalization + PV (validated round 4; unchanged).
// ---------------------------------------------------------------------------
#define PPAD 136
#define VPAD 40

__global__ __launch_bounds__(256, 2)
void attn_pdg_mfma(const _Float16* __restrict__ QKV, const float* __restrict__ Rel,
                   _Float16* __restrict__ resh)
{
    __shared__ __align__(16) char smem[72704];
    _Float16* P     = (_Float16*)smem;
    _Float16* Qs    = (_Float16*)(smem + 34816);
    _Float16* Ks    = Qs + 2 * 4096;
    _Float16* Vt    = (_Float16*)(smem + 34816);
    unsigned* rbits = (unsigned*)(smem + 67584);
    float* rowpart  = (float*)(smem + 69632);
    float* colpart  = (float*)(smem + 70656);
    float* inv_in   = (float*)(smem + 71680);
    float* inv_out  = (float*)(smem + 72192);

    const int tid = threadIdx.x;
    const int w = tid >> 6, l = tid & 63;
    const int wr = w >> 1, wc = w & 1;
    const int lr = l & 15, lg = l >> 4;
    const int b = blockIdx.x, h = blockIdx.y;

    for (int s = w; s < S_; s += 4) {
        const float* row = &Rel[((size_t)b * S_ + s) * S_];
        unsigned long long b0 = __ballot(row[l] > 0.5f);
        unsigned long long b1 = __ballot(row[64 + l] > 0.5f);
        if (l == 0) {
            rbits[s * 4 + 0] = (unsigned)b0; rbits[s * 4 + 1] = (unsigned)(b0 >> 32);
            rbits[s * 4 + 2] = (unsigned)b1; rbits[s * 4 + 3] = (unsigned)(b1 >> 32);
        }
    }

    const size_t gbase = (size_t)(b * S_) * 3072 + h * DH_;

    auto stageQK = [&](int bufi, int t) {
        const int k0 = t * 32;
        const int rr = l >> 2, cc = (l & 3) * 8;
        #pragma unroll
        for (int i = 0; i < 2; ++i) {
            const int row = w * 32 + i * 16;
            const _Float16* gq = QKV + gbase + (size_t)(row + rr) * 3072 + k0 + cc;
            GLOAD_LDS16(gq, Qs + bufi * 4096 + row * 32);
            const _Float16* gk = QKV + gbase + 1024 + (size_t)(row + rr) * 3072 + k0 + cc;
            GLOAD_LDS16(gk, Ks + bufi * 4096 + row * 32);
        }
    };

    f32x4 acc[4][4] = {};
    stageQK(0, 0);
    __syncthreads();
    int buf = 0;
    for (int t = 0; t < 4; ++t) {
        if (t < 3) stageQK(buf ^ 1, t + 1);
        half8 af[4], bf[4];
        #pragma unroll
        for (int i = 0; i < 4; ++i)
            af[i] = *(const half8*)&Qs[buf * 4096 + (wr * 64 + i * 16 + lr) * 32 + lg * 8];
        #pragma unroll
        for (int j = 0; j < 4; ++j)
            bf[j] = *(const half8*)&Ks[buf * 4096 + (wc * 64 + j * 16 + lr) * 32 + lg * 8];
        #pragma unroll
        for (int i = 0; i < 4; ++i)
            #pragma unroll
            for (int j = 0; j < 4; ++j)
                acc[i][j] = __builtin_amdgcn_mfma_f32_16x16x32_f16(af[i], bf[j], acc[i][j], 0, 0, 0);
        __syncthreads();
        buf ^= 1;
    }

    auto relf = [&](int s, int t) -> float {
        float r;
        if (h < H_ / 2) {
            r = (float)((rbits[s * 4 + (t >> 5)] >> (t & 31)) & 1u);
            if (s == t) r += (float)h;
        } else {
            r = (float)((rbits[t * 4 + (s >> 5)] >> (s & 31)) & 1u);
        }
        return r;
    };

    f32x4 p[4][4];
    #pragma unroll
    for (int i = 0; i < 4; ++i)
        #pragma unroll
        for (int j = 0; j < 4; ++j)
            #pragma unroll
            for (int rg = 0; rg < 4; ++rg) {
                const int s = wr * 64 + i * 16 + lg * 4 + rg;
                const int t = wc * 64 + j * 16 + lr;
                p[i][j][rg] = relf(s, t) * acc[i][j][rg] + 1e-11f;
            }

    #pragma unroll
    for (int i = 0; i < 4; ++i)
        #pragma unroll
        for (int rg = 0; rg < 4; ++rg) {
            float part = p[i][0][rg] + p[i][1][rg] + p[i][2][rg] + p[i][3][rg];
            part += __shfl_xor(part, 1);
            part += __shfl_xor(part, 2);
            part += __shfl_xor(part, 4);
            part += __shfl_xor(part, 8);
            if (lr == 0) rowpart[wc * 128 + wr * 64 + i * 16 + lg * 4 + rg] = part;
        }
    #pragma unroll
    for (int j = 0; j < 4; ++j) {
        float part = 0.0f;
        #pragma unroll
        for (int i = 0; i < 4; ++i)
            part += p[i][j][0] + p[i][j][1] + p[i][j][2] + p[i][j][3];
        part += __shfl_xor(part, 16);
        part += __shfl_xor(part, 32);
        if (lg == 0) colpart[wr * 128 + wc * 64 + j * 16 + lr] = part;
    }
    __syncthreads();

    if (tid < 128) {
        inv_in[tid] = rsqrtf(colpart[tid] + colpart[128 + tid]);
    } else {
        const int s = tid - 128;
        inv_out[s] = rsqrtf(rowpart[s] + rowpart[128 + s]);
    }
    __syncthreads();

    float itj[4];
    #pragma unroll
    for (int j = 0; j < 4; ++j) itj[j] = inv_in[wc * 64 + j * 16 + lr];
    #pragma unroll
    for (int i = 0; i < 4; ++i)
        #pragma unroll
        for (int rg = 0; rg < 4; ++rg) {
            const int s = wr * 64 + i * 16 + lg * 4 + rg;
            const float os = inv_out[s];
            #pragma unroll
            for (int j = 0; j < 4; ++j) {
                const int t = wc * 64 + j * 16 + lr;
                const float val = relf(s, t) * p[i][j][rg] * itj[j] * os;
                P[s * PPAD + t] = (_Float16)val;
            }
        }

    const _Float16* Vb = QKV + gbase + 2048;
    uint4 vreg[2];
    auto loadV = [&](int t) {
        #pragma unroll
        for (int ii = 0; ii < 2; ++ii) {
            const int unit = tid + ii * 256;
            const int tt = unit & 31, fg = unit >> 5;
            vreg[ii] = *(const uint4*)&Vb[(size_t)(t * 32 + tt) * 3072 + fg * 8];
        }
    };

    loadV(0);
    f32x4 acc2[4][4] = {};
    for (int t = 0; t < 4; ++t) {
        #pragma unroll
        for (int ii = 0; ii < 2; ++ii) {
            union { uint4 u; _Float16 hh[8]; } uu;
            uu.u = vreg[ii];
            const int unit = tid + ii * 256;
            const int tt = unit & 31, fg = unit >> 5;
            #pragma unroll
            for (int e = 0; e < 8; ++e)
                Vt[(fg * 8 + e) * VPAD + tt] = uu.hh[e];
        }
        __syncthreads();
        if (t < 3) loadV(t + 1);

        half8 af[4], bf[4];
        #pragma unroll
        for (int i = 0; i < 4; ++i)
            af[i] = *(const half8*)&P[(wr * 64 + i * 16 + lr) * PPAD + t * 32 + lg * 8];
        #pragma unroll
        for (int j = 0; j < 4; ++j)
            bf[j] = *(const half8*)&Vt[(wc * 64 + j * 16 + lr) * VPAD + lg * 8];
        #pragma unroll
        for (int i = 0; i < 4; ++i)
            #pragma unroll
            for (int j = 0; j < 4; ++j)
                acc2[i][j] = __builtin_amdgcn_mfma_f32_16x16x32_f16(af[i], bf[j], acc2[i][j], 0, 0, 0);
        __syncthreads();
    }

    #pragma unroll
    for (int i = 0; i < 4; ++i)
        #pragma unroll
        for (int rg = 0; rg < 4; ++rg) {
            const int s = wr * 64 + i * 16 + lg * 4 + rg;
            #pragma unroll
            for (int j = 0; j < 4; ++j) {
                const int f = wc * 64 + j * 16 + lr;
                resh[((size_t)(b * S_ + s)) * 1024 + h * DH_ + f] = (_Float16)acc2[i][j][rg];
            }
        }
}

// ---------------------------------------------------------------------------
extern "C" void kernel_launch(void* const* d_in, const int* in_sizes, int n_in,
                              void* d_out, int out_size, void* d_ws, size_t ws_size,
                              hipStream_t stream)
{
    const float* code = (const float*)d_in[0];
    const float* Rel  = (const float*)d_in[1];
    const float* Wq   = (const float*)d_in[2];
    const float* bq   = (const float*)d_in[3];
    const float* Wk   = (const float*)d_in[4];
    const float* bk   = (const float*)d_in[5];
    const float* Wv   = (const float*)d_in[6];
    const float* bv   = (const float*)d_in[7];
    const float* Wo   = (const float*)d_in[8];
    const float* bo   = (const float*)d_in[9];
    float* out = (float*)d_out;
    (void)in_sizes; (void)n_in; (void)out_size; (void)ws_size;

    char* wsp = (char*)d_ws;
    _Float16* codeh = (_Float16*)wsp;  wsp += (size_t)M_ * 1024 * 2;
    _Float16* QKV   = (_Float16*)wsp;  wsp += (size_t)M_ * 3072 * 2;
    _Float16* resh  = (_Float16*)wsp;  wsp += (size_t)M_ * 1024 * 2;
    _Float16* Wt    = (_Float16*)wsp;  wsp += (size_t)3072 * 1024 * 2;
    _Float16* Wot   = (_Float16*)wsp;  wsp += (size_t)1024 * 2048 * 2;
    float* bias_all = (float*)wsp;     wsp += 3072 * 4;

    cvt_code<<<(M_ * 1024 / 8 + 255) / 256, 256, 0, stream>>>(code, codeh, M_ * 1024 / 8);
    cvt_wqkv<<<(3072 * 128 + 255) / 256, 256, 0, stream>>>(Wq, Wk, Wv, bq, bk, bv, Wt, bias_all);
    cvt_wo<<<(1024 * 256 + 255) / 256, 256, 0, stream>>>(Wo, Wot);

    // QKV projection: [M,1024] x [1024,3072] -> QKV f16 [M][3072]
    gemm_f16_8p<false><<<(M_ / 256) * (3072 / 256), 512, 0, stream>>>(
        codeh, codeh, 1024, Wt, bias_all, (void*)QKV, 3072, 1024, 3072 / 256);

    attn_pdg_mfma<<<dim3(B_, H_), 256, 0, stream>>>(QKV, Rel, resh);

    // Output projection: [M, 2048(=resh|codeh)] x [2048,1024] -> out f32
    gemm_f16_8p<true><<<(M_ / 256) * (1024 / 256), 512, 0, stream>>>(
        resh, codeh, 1024, Wot, bo, (void*)out, 1024, 2048, 1024 / 256);
}

// Round 8
// 576.224 us; speedup vs baseline: 1.0123x; 1.0123x over previous
//
#include <hip/hip_runtime.h>
#include <cstdint>
#include <cstddef>

// Problem constants
#define B_  256
#define S_  128
#define D_  1024
#define H_  8
#define DH_ 128
#define M_  (B_ * S_)   // 32768 rows

typedef _Float16 half8 __attribute__((ext_vector_type(8)));
typedef float    f32x4 __attribute__((ext_vector_type(4)));

#define GLOAD_LDS16(gp, lp)                                                    \
    __builtin_amdgcn_global_load_lds(                                          \
        (const __attribute__((address_space(1))) void*)(gp),                   \
        (__attribute__((address_space(3))) void*)(lp), 16, 0, 0)

// ---------------------------------------------------------------------------
// Conversion kernels
// ---------------------------------------------------------------------------
__global__ __launch_bounds__(256)
void cvt_code(const float* __restrict__ src, _Float16* __restrict__ dst, int n8)
{
    int i = blockIdx.x * 256 + threadIdx.x;
    if (i >= n8) return;
    const float4* s = (const float4*)src;
    float4 a = s[2 * i], b = s[2 * i + 1];
    half8 o;
    o[0] = (_Float16)a.x; o[1] = (_Float16)a.y; o[2] = (_Float16)a.z; o[3] = (_Float16)a.w;
    o[4] = (_Float16)b.x; o[5] = (_Float16)b.y; o[6] = (_Float16)b.z; o[7] = (_Float16)b.w;
    *(half8*)(dst + (size_t)i * 8) = o;
}

__global__ __launch_bounds__(256)
void cvt_wqkv(const float* __restrict__ Wq, const float* __restrict__ Wk,
              const float* __restrict__ Wv,
              const float* __restrict__ bq, const float* __restrict__ bk,
              const float* __restrict__ bv,
              _Float16* __restrict__ Wt, float* __restrict__ bias_all)
{
    int idx = blockIdx.x * 256 + threadIdx.x;   // 3072*128
    if (idx >= 3072 * 128) return;
    int n = idx >> 7, kc = idx & 127, k = kc * 8;
    int qkv = n >> 10, hf = n & 1023, h = hf >> 7, f = hf & 127;
    const float* W = (qkv == 0 ? Wq : (qkv == 1 ? Wk : Wv))
                     + (size_t)h * D_ * DH_ + (size_t)k * DH_ + f;
    half8 o;
    #pragma unroll
    for (int j = 0; j < 8; ++j) o[j] = (_Float16)W[(size_t)j * DH_];
    *(half8*)(Wt + (size_t)n * 1024 + k) = o;
    if (kc == 0)
        bias_all[n] = (qkv == 0 ? bq : (qkv == 1 ? bk : bv))[h * DH_ + f];
}

__global__ __launch_bounds__(256)
void cvt_wo(const float* __restrict__ Wo, _Float16* __restrict__ Wot)
{
    int idx = blockIdx.x * 256 + threadIdx.x;   // 1024*256
    if (idx >= 1024 * 256) return;
    int n = idx >> 8, kc = idx & 255, k = kc * 8;
    const float* W = Wo + (size_t)k * 1024 + n;
    half8 o;
    #pragma unroll
    for (int j = 0; j < 8; ++j) o[j] = (_Float16)W[(size_t)j * 1024];
    *(half8*)(Wot + (size_t)n * 2048 + k) = o;
}

// ---------------------------------------------------------------------------
// 256x256 f16 MFMA GEMM, full-tile-prefetch schedule.
// ROUND 8: one publication point per K-tile. At tile t's head:
//   vmcnt(0)  -- waits loads issued a FULL TILE ago (~1700 cyc cover: free)
//   raw s_barrier -- publication + WAR fence (raw: no forced drain of new loads)
//   issue ALL 4 halves of tile t+1 (8 gload_lds/wave)
//   compute 4 quadrants with NO mid-tile publication waits; plain ds_reads
//   (compiler inserts counted lgkmcnt); one mid-tile barrier as sched fence.
// This removes the 3 per-tile vmcnt stalls that r5-r7 profiling showed were
// the real cost (issue-to-wait distance was < L2/HBM latency).
// ---------------------------------------------------------------------------
template <bool OUTF32>
__global__ __launch_bounds__(512, 1)
void gemm_f16_8p(const _Float16* __restrict__ A1p, const _Float16* __restrict__ A2p,
                 int K1, const _Float16* __restrict__ Bt,
                 const float* __restrict__ bias, void* __restrict__ outp,
                 int Ntot, int Ktot, int ntn)
{
    __shared__ __align__(16) char lds[131072];

    const int tid = threadIdx.x;
    const int w = tid >> 6, l = tid & 63;
    const int wm = w >> 2, wn = w & 3;
    const int lr = l & 15, lg = l >> 4;

    // Bijective XCD swizzle (gridDim.x % 8 == 0), n-fastest decode.
    const int cpx = gridDim.x >> 3;
    const int bid = blockIdx.x;
    const int swz = (bid & 7) * cpx + (bid >> 3);
    const int m0 = (swz / ntn) * 256, n0 = (swz % ntn) * 256;

    const int NT = Ktot >> 6;

    // staging lane geometry
    const int srow  = l >> 3;                   // row within 8-row chunk
    const int sgcol = ((l & 7) ^ srow) * 8;     // pre-swizzled source col (f16)

    // half: 0=A0, 1=B0, 2=B1, 3=A1
    auto stageHalf = [&](int bufi, int t, int half) {
        const int k0 = t << 6;
        const bool isA = (half == 0) || (half == 3);
        const int hh = (half >= 2) ? 1 : 0;
        char* dst0 = lds + bufi * 65536 + (isA ? 0 : 32768) + hh * 16384;
        if (isA) {
            const _Float16* Asrc; int kc;
            if (k0 < K1) { Asrc = A1p; kc = k0; } else { Asrc = A2p; kc = k0 - K1; }
            #pragma unroll
            for (int i = 0; i < 2; ++i) {
                const int c = i * 8 + w;
                const int row = hh * 128 + c * 8 + srow;
                const _Float16* g = Asrc + (size_t)(m0 + row) * 1024 + kc + sgcol;
                GLOAD_LDS16(g, dst0 + c * 1024);
            }
        } else {
            #pragma unroll
            for (int i = 0; i < 2; ++i) {
                const int c = i * 8 + w;
                const int row = hh * 128 + c * 8 + srow;
                const _Float16* g = Bt + (size_t)(n0 + row) * Ktot + k0 + sgcol;
                GLOAD_LDS16(g, dst0 + c * 1024);
            }
        }
    };

    auto ldA = [&](int bufi, int fi, int ks) -> half8 {
        const int row = fi * 32 + wm * 16 + lr;
        const int pos = (ks * 4 + lg) ^ (row & 7);
        return *(const half8*)(lds + bufi * 65536 + row * 128 + pos * 16);
    };
    auto ldB = [&](int bufi, int fj, int ks) -> half8 {
        const int row = fj * 64 + wn * 16 + lr;
        const int pos = (ks * 4 + lg) ^ (row & 7);
        return *(const half8*)(lds + bufi * 65536 + 32768 + row * 128 + pos * 16);
    };

    f32x4 acc[8][4] = {};
    half8 aq[4][2], b0[2][2], b1[2][2];

    // Prologue: stage tile 0 (all 4 halves).
    stageHalf(0, 0, 0); stageHalf(0, 0, 1); stageHalf(0, 0, 2); stageHalf(0, 0, 3);

    for (int t = 0; t < NT; ++t) {
        const int buf = t & 1;
        const bool nl = (t + 1 < NT);

        // Publication: tile t's 8 loads were issued one full tile ago.
        asm volatile("s_waitcnt vmcnt(0)" ::: "memory");
        __builtin_amdgcn_s_barrier();

        // Prefetch ALL of tile t+1 into buf^1 (lands any time before next head).
        if (nl) {
            stageHalf(buf ^ 1, t + 1, 0); stageHalf(buf ^ 1, t + 1, 1);
            stageHalf(buf ^ 1, t + 1, 2); stageHalf(buf ^ 1, t + 1, 3);
        }

        // ---- First half-tile: quadrants q00 (aqA x b0) and q01 (aqA x b1).
        #pragma unroll
        for (int fi = 0; fi < 4; ++fi)
            #pragma unroll
            for (int ks = 0; ks < 2; ++ks)
                aq[fi][ks] = ldA(buf, fi, ks);
        #pragma unroll
        for (int fj = 0; fj < 2; ++fj)
            #pragma unroll
            for (int ks = 0; ks < 2; ++ks)
                b0[fj][ks] = ldB(buf, fj, ks);
        #pragma unroll
        for (int fj = 0; fj < 2; ++fj)
            #pragma unroll
            for (int ks = 0; ks < 2; ++ks)
                b1[fj][ks] = ldB(buf, fj + 2, ks);

        __builtin_amdgcn_s_setprio(1);
        #pragma unroll
        for (int ks = 0; ks < 2; ++ks)
            #pragma unroll
            for (int fi = 0; fi < 4; ++fi)
                #pragma unroll
                for (int fj = 0; fj < 2; ++fj)
                    acc[fi][fj] = __builtin_amdgcn_mfma_f32_16x16x32_f16(
                        aq[fi][ks], b0[fj][ks], acc[fi][fj], 0, 0, 0);
        #pragma unroll
        for (int ks = 0; ks < 2; ++ks)
            #pragma unroll
            for (int fi = 0; fi < 4; ++fi)
                #pragma unroll
                for (int fj = 0; fj < 2; ++fj)
                    acc[fi][fj + 2] = __builtin_amdgcn_mfma_f32_16x16x32_f16(
                        aq[fi][ks], b1[fj][ks], acc[fi][fj + 2], 0, 0, 0);
        __builtin_amdgcn_s_setprio(0);

        // Mid-tile fence (scheduling/pressure bound; no publication semantics).
        __builtin_amdgcn_s_barrier();

        // ---- Second half-tile: quadrants q11 (aqB x b1) and q10 (aqB x b0).
        #pragma unroll
        for (int fi = 0; fi < 4; ++fi)
            #pragma unroll
            for (int ks = 0; ks < 2; ++ks)
                aq[fi][ks] = ldA(buf, fi + 4, ks);

        __builtin_amdgcn_s_setprio(1);
        #pragma unroll
        for (int ks = 0; ks < 2; ++ks)
            #pragma unroll
            for (int fi = 0; fi < 4; ++fi)
                #pragma unroll
                for (int fj = 0; fj < 2; ++fj)
                    acc[fi + 4][fj + 2] = __builtin_amdgcn_mfma_f32_16x16x32_f16(
                        aq[fi][ks], b1[fj][ks], acc[fi + 4][fj + 2], 0, 0, 0);
        #pragma unroll
        for (int ks = 0; ks < 2; ++ks)
            #pragma unroll
            for (int fi = 0; fi < 4; ++fi)
                #pragma unroll
                for (int fj = 0; fj < 2; ++fj)
                    acc[fi + 4][fj] = __builtin_amdgcn_mfma_f32_16x16x32_f16(
                        aq[fi][ks], b0[fj][ks], acc[fi + 4][fj], 0, 0, 0);
        __builtin_amdgcn_s_setprio(0);
    }

    // Epilogue: bias + relu + store
    #pragma unroll
    for (int fi = 0; fi < 8; ++fi) {
        #pragma unroll
        for (int fj = 0; fj < 4; ++fj) {
            const int n = n0 + fj * 64 + wn * 16 + lr;
            const float bs = bias[n];
            #pragma unroll
            for (int rg = 0; rg < 4; ++rg) {
                const int m = m0 + fi * 32 + wm * 16 + lg * 4 + rg;
                float v = acc[fi][fj][rg] + bs;
                v = v > 0.0f ? v : 0.0f;
                if constexpr (OUTF32)
                    ((float*)outp)[(size_t)m * Ntot + n] = v;
                else
                    ((_Float16*)outp)[(size_t)m * Ntot + n] = (_Float16)v;
            }
        }
    }
}

// ---------------------------------------------------------------------------
// MFMA attention + PDG normalization + PV (validated round 4; unchanged).
// ---------------------------------------------------------------------------
#define PPAD 136
#define VPAD 40

__global__ __launch_bounds__(256, 2)
void attn_pdg_mfma(const _Float16* __restrict__ QKV, const float* __restrict__ Rel,
                   _Float16* __restrict__ resh)
{
    __shared__ __align__(16) char smem[72704];
    _Float16* P     = (_Float16*)smem;
    _Float16* Qs    = (_Float16*)(smem + 34816);
    _Float16* Ks    = Qs + 2 * 4096;
    _Float16* Vt    = (_Float16*)(smem + 34816);
    unsigned* rbits = (unsigned*)(smem + 67584);
    float* rowpart  = (float*)(smem + 69632);
    float* colpart  = (float*)(smem + 70656);
    float* inv_in   = (float*)(smem + 71680);
    float* inv_out  = (float*)(smem + 72192);

    const int tid = threadIdx.x;
    const int w = tid >> 6, l = tid & 63;
    const int wr = w >> 1, wc = w & 1;
    const int lr = l & 15, lg = l >> 4;
    const int b = blockIdx.x, h = blockIdx.y;

    for (int s = w; s < S_; s += 4) {
        const float* row = &Rel[((size_t)b * S_ + s) * S_];
        unsigned long long b0 = __ballot(row[l] > 0.5f);
        unsigned long long b1 = __ballot(row[64 + l] > 0.5f);
        if (l == 0) {
            rbits[s * 4 + 0] = (unsigned)b0; rbits[s * 4 + 1] = (unsigned)(b0 >> 32);
            rbits[s * 4 + 2] = (unsigned)b1; rbits[s * 4 + 3] = (unsigned)(b1 >> 32);
        }
    }

    const size_t gbase = (size_t)(b * S_) * 3072 + h * DH_;

    auto stageQK = [&](int bufi, int t) {
        const int k0 = t * 32;
        const int rr = l >> 2, cc = (l & 3) * 8;
        #pragma unroll
        for (int i = 0; i < 2; ++i) {
            const int row = w * 32 + i * 16;
            const _Float16* gq = QKV + gbase + (size_t)(row + rr) * 3072 + k0 + cc;
            GLOAD_LDS16(gq, Qs + bufi * 4096 + row * 32);
            const _Float16* gk = QKV + gbase + 1024 + (size_t)(row + rr) * 3072 + k0 + cc;
            GLOAD_LDS16(gk, Ks + bufi * 4096 + row * 32);
        }
    };

    f32x4 acc[4][4] = {};
    stageQK(0, 0);
    __syncthreads();
    int buf = 0;
    for (int t = 0; t < 4; ++t) {
        if (t < 3) stageQK(buf ^ 1, t + 1);
        half8 af[4], bf[4];
        #pragma unroll
        for (int i = 0; i < 4; ++i)
            af[i] = *(const half8*)&Qs[buf * 4096 + (wr * 64 + i * 16 + lr) * 32 + lg * 8];
        #pragma unroll
        for (int j = 0; j < 4; ++j)
            bf[j] = *(const half8*)&Ks[buf * 4096 + (wc * 64 + j * 16 + lr) * 32 + lg * 8];
        #pragma unroll
        for (int i = 0; i < 4; ++i)
            #pragma unroll
            for (int j = 0; j < 4; ++j)
                acc[i][j] = __builtin_amdgcn_mfma_f32_16x16x32_f16(af[i], bf[j], acc[i][j], 0, 0, 0);
        __syncthreads();
        buf ^= 1;
    }

    auto relf = [&](int s, int t) -> float {
        float r;
        if (h < H_ / 2) {
            r = (float)((rbits[s * 4 + (t >> 5)] >> (t & 31)) & 1u);
            if (s == t) r += (float)h;
        } else {
            r = (float)((rbits[t * 4 + (s >> 5)] >> (s & 31)) & 1u);
        }
        return r;
    };

    f32x4 p[4][4];
    #pragma unroll
    for (int i = 0; i < 4; ++i)
        #pragma unroll
        for (int j = 0; j < 4; ++j)
            #pragma unroll
            for (int rg = 0; rg < 4; ++rg) {
                const int s = wr * 64 + i * 16 + lg * 4 + rg;
                const int t = wc * 64 + j * 16 + lr;
                p[i][j][rg] = relf(s, t) * acc[i][j][rg] + 1e-11f;
            }

    #pragma unroll
    for (int i = 0; i < 4; ++i)
        #pragma unroll
        for (int rg = 0; rg < 4; ++rg) {
            float part = p[i][0][rg] + p[i][1][rg] + p[i][2][rg] + p[i][3][rg];
            part += __shfl_xor(part, 1);
            part += __shfl_xor(part, 2);
            part += __shfl_xor(part, 4);
            part += __shfl_xor(part, 8);
            if (lr == 0) rowpart[wc * 128 + wr * 64 + i * 16 + lg * 4 + rg] = part;
        }
    #pragma unroll
    for (int j = 0; j < 4; ++j) {
        float part = 0.0f;
        #pragma unroll
        for (int i = 0; i < 4; ++i)
            part += p[i][j][0] + p[i][j][1] + p[i][j][2] + p[i][j][3];
        part += __shfl_xor(part, 16);
        part += __shfl_xor(part, 32);
        if (lg == 0) colpart[wr * 128 + wc * 64 + j * 16 + lr] = part;
    }
    __syncthreads();

    if (tid < 128) {
        inv_in[tid] = rsqrtf(colpart[tid] + colpart[128 + tid]);
    } else {
        const int s = tid - 128;
        inv_out[s] = rsqrtf(rowpart[s] + rowpart[128 + s]);
    }
    __syncthreads();

    float itj[4];
    #pragma unroll
    for (int j = 0; j < 4; ++j) itj[j] = inv_in[wc * 64 + j * 16 + lr];
    #pragma unroll
    for (int i = 0; i < 4; ++i)
        #pragma unroll
        for (int rg = 0; rg < 4; ++rg) {
            const int s = wr * 64 + i * 16 + lg * 4 + rg;
            const float os = inv_out[s];
            #pragma unroll
            for (int j = 0; j < 4; ++j) {
                const int t = wc * 64 + j * 16 + lr;
                const float val = relf(s, t) * p[i][j][rg] * itj[j] * os;
                P[s * PPAD + t] = (_Float16)val;
            }
        }

    const _Float16* Vb = QKV + gbase + 2048;
    uint4 vreg[2];
    auto loadV = [&](int t) {
        #pragma unroll
        for (int ii = 0; ii < 2; ++ii) {
            const int unit = tid + ii * 256;
            const int tt = unit & 31, fg = unit >> 5;
            vreg[ii] = *(const uint4*)&Vb[(size_t)(t * 32 + tt) * 3072 + fg * 8];
        }
    };

    loadV(0);
    f32x4 acc2[4][4] = {};
    for (int t = 0; t < 4; ++t) {
        #pragma unroll
        for (int ii = 0; ii < 2; ++ii) {
            union { uint4 u; _Float16 hh[8]; } uu;
            uu.u = vreg[ii];
            const int unit = tid + ii * 256;
            const int tt = unit & 31, fg = unit >> 5;
            #pragma unroll
            for (int e = 0; e < 8; ++e)
                Vt[(fg * 8 + e) * VPAD + tt] = uu.hh[e];
        }
        __syncthreads();
        if (t < 3) loadV(t + 1);

        half8 af[4], bf[4];
        #pragma unroll
        for (int i = 0; i < 4; ++i)
            af[i] = *(const half8*)&P[(wr * 64 + i * 16 + lr) * PPAD + t * 32 + lg * 8];
        #pragma unroll
        for (int j = 0; j < 4; ++j)
            bf[j] = *(const half8*)&Vt[(wc * 64 + j * 16 + lr) * VPAD + lg * 8];
        #pragma unroll
        for (int i = 0; i < 4; ++i)
            #pragma unroll
            for (int j = 0; j < 4; ++j)
                acc2[i][j] = __builtin_amdgcn_mfma_f32_16x16x32_f16(af[i], bf[j], acc2[i][j], 0, 0, 0);
        __syncthreads();
    }

    #pragma unroll
    for (int i = 0; i < 4; ++i)
        #pragma unroll
        for (int rg = 0; rg < 4; ++rg) {
            const int s = wr * 64 + i * 16 + lg * 4 + rg;
            #pragma unroll
            for (int j = 0; j < 4; ++j) {
                const int f = wc * 64 + j * 16 + lr;
                resh[((size_t)(b * S_ + s)) * 1024 + h * DH_ + f] = (_Float16)acc2[i][j][rg];
            }
        }
}

// ---------------------------------------------------------------------------
extern "C" void kernel_launch(void* const* d_in, const int* in_sizes, int n_in,
                              void* d_out, int out_size, void* d_ws, size_t ws_size,
                              hipStream_t stream)
{
    const float* code = (const float*)d_in[0];
    const float* Rel  = (const float*)d_in[1];
    const float* Wq   = (const float*)d_in[2];
    const float* bq   = (const float*)d_in[3];
    const float* Wk   = (const float*)d_in[4];
    const float* bk   = (const float*)d_in[5];
    const float* Wv   = (const float*)d_in[6];
    const float* bv   = (const float*)d_in[7];
    const float* Wo   = (const float*)d_in[8];
    const float* bo   = (const float*)d_in[9];
    float* out = (float*)d_out;
    (void)in_sizes; (void)n_in; (void)out_size; (void)ws_size;

    char* wsp = (char*)d_ws;
    _Float16* codeh = (_Float16*)wsp;  wsp += (size_t)M_ * 1024 * 2;
    _Float16* QKV   = (_Float16*)wsp;  wsp += (size_t)M_ * 3072 * 2;
    _Float16* resh  = (_Float16*)wsp;  wsp += (size_t)M_ * 1024 * 2;
    _Float16* Wt    = (_Float16*)wsp;  wsp += (size_t)3072 * 1024 * 2;
    _Float16* Wot   = (_Float16*)wsp;  wsp += (size_t)1024 * 2048 * 2;
    float* bias_all = (float*)wsp;     wsp += 3072 * 4;

    cvt_code<<<(M_ * 1024 / 8 + 255) / 256, 256, 0, stream>>>(code, codeh, M_ * 1024 / 8);
    cvt_wqkv<<<(3072 * 128 + 255) / 256, 256, 0, stream>>>(Wq, Wk, Wv, bq, bk, bv, Wt, bias_all);
    cvt_wo<<<(1024 * 256 + 255) / 256, 256, 0, stream>>>(Wo, Wot);

    // QKV projection: [M,1024] x [1024,3072] -> QKV f16 [M][3072]
    gemm_f16_8p<false><<<(M_ / 256) * (3072 / 256), 512, 0, stream>>>(
        codeh, codeh, 1024, Wt, bias_all, (void*)QKV, 3072, 1024, 3072 / 256);

    attn_pdg_mfma<<<dim3(B_, H_), 256, 0, stream>>>(QKV, Rel, resh);

    // Output projection: [M, 2048(=resh|codeh)] x [2048,1024] -> out f32
    gemm_f16_8p<true><<<(M_ / 256) * (1024 / 256), 512, 0, stream>>>(
        resh, codeh, 1024, Wot, bo, (void*)out, 1024, 2048, 1024 / 256);
}